// Round 2
// baseline (333.886 us; speedup 1.0000x reference)
//
#include <hip/hip_runtime.h>
#include <cstdint>
#include <cstddef>

// GGCN layer fused kernels for MI355X (gfx950).  B=2, N=256, D=256 fixed.
//
// ws float layout:
//   Ah  [512*256] @ 0
//   Bh  [512*256] @ 131072
//   Uh  [512*256] @ 262144
//   Vh  [512*256] @ 393216
//   msgs[512*256] @ 524288
//   wc bf16 (pre-permuted, slab/kg-major) @ byte 2621440, 131072 bytes
// total ws need = 2752512 bytes.

#define AH_OFF 0
#define BH_OFF 131072
#define UH_OFF 262144
#define VH_OFF 393216
#define MS_OFF 524288
#define WC_BYTE_OFF 2621440

typedef __attribute__((ext_vector_type(4))) float vfloat4;
typedef __attribute__((ext_vector_type(4))) short vshort4;
typedef __attribute__((ext_vector_type(8))) short vshort8;

__device__ inline unsigned short bf16_rne(float x) {
    unsigned u = __builtin_bit_cast(unsigned, x);
    u += 0x7fffu + ((u >> 16) & 1u);
    return (unsigned short)(u >> 16);
}

__device__ inline void gload_lds16(const void* g, void* l) {
    __builtin_amdgcn_global_load_lds(
        (const __attribute__((address_space(1))) void*)g,
        (__attribute__((address_space(3))) void*)l, 16, 0, 0);
}

__device__ inline vfloat4 mfma_16x16x32_bf16(vshort8 a, vshort8 b, vfloat4 c) {
    asm("v_mfma_f32_16x16x32_bf16 %0, %1, %2, %0" : "+v"(c) : "v"(a), "v"(b));
    return c;
}

// ---------------------------------------------------------------------------
// prep: blocks 0..127   -> Ah/Bh/Uh/Vh (fp32 exact, 4 rows each)
//       blocks 128..191 -> WC -> bf16, permuted to [slab(8)][kg(4)][d(256)][e(8)]
//       blocks 192..255 -> zero msgs
// ---------------------------------------------------------------------------
__global__ void __launch_bounds__(256)
ggcn_prep(const float* __restrict__ h,
          const float* __restrict__ WA, const float* __restrict__ bA,
          const float* __restrict__ WB, const float* __restrict__ bB,
          const float* __restrict__ WC,
          const float* __restrict__ WU, const float* __restrict__ bU,
          const float* __restrict__ WV, const float* __restrict__ bV,
          float* __restrict__ ws) {
    int bid = blockIdx.x, tid = threadIdx.x;
    if (bid < 128) {
        __shared__ float hs[4][256];
        int gm0 = bid * 4;
        vfloat4 hv = *(const vfloat4*)(h + gm0 * 256 + tid * 4);
        ((vfloat4*)(&hs[0][0]))[tid] = hv;
        __syncthreads();
        float aA[4] = {0, 0, 0, 0}, aB[4] = {0, 0, 0, 0};
        float aU[4] = {0, 0, 0, 0}, aV[4] = {0, 0, 0, 0};
        int d = tid;
        for (int k = 0; k < 256; ++k) {
            float wa = WA[k * 256 + d], wb = WB[k * 256 + d];
            float wu = WU[k * 256 + d], wv = WV[k * 256 + d];
#pragma unroll
            for (int mm = 0; mm < 4; ++mm) {
                float hh = hs[mm][k];
                aA[mm] = fmaf(hh, wa, aA[mm]);
                aB[mm] = fmaf(hh, wb, aB[mm]);
                aU[mm] = fmaf(hh, wu, aU[mm]);
                aV[mm] = fmaf(hh, wv, aV[mm]);
            }
        }
        float ba = bA[d], bb = bB[d], bu = bU[d], bv = bV[d];
#pragma unroll
        for (int mm = 0; mm < 4; ++mm) {
            int o = (gm0 + mm) * 256 + d;
            ws[AH_OFF + o] = aA[mm] + ba;
            ws[BH_OFF + o] = aB[mm] + bb;
            ws[UH_OFF + o] = aU[mm] + bu;
            ws[VH_OFF + o] = aV[mm] + bv;
        }
    } else if (bid < 192) {
        // wc[idx]: idx = slab*8192 + kg*2048 + d*8 + e ; k = slab*32 + kg*8 + e
        unsigned short* wc = (unsigned short*)((char*)ws + WC_BYTE_OFF);
        int local = bid - 128;
#pragma unroll
        for (int r = 0; r < 4; ++r) {
            int idx = local * 1024 + r * 256 + tid;
            int slab = idx >> 13;
            int rem = idx & 8191;
            int kg = rem >> 11;
            int d = (rem >> 3) & 255;
            int e = rem & 7;
            int k = slab * 32 + kg * 8 + e;
            wc[idx] = bf16_rne(WC[k * 256 + d]);
        }
    } else {
        int local = bid - 192;
#pragma unroll
        for (int r = 0; r < 8; ++r)
            ws[MS_OFF + local * 2048 + r * 256 + tid] = 0.f;
    }
}

// ---------------------------------------------------------------------------
// main: grid 4096 = 512 rows x 8 j-tiles of 32. block 256 thr (4 waves).
// LDS 64KB -> 2 blocks/CU:
//   A_hi [kg32][slot32][8e] @0      (16K)   byte(j,k)=kg*512+((j^kg)<<4)+(k&7)*2
//   A_lo                 @16384     (16K)
//   B dbuf 2x [kg4][d256][8e] @32768 (2x16K) byte(d,kl)=kg*4096+d*16+(kl&7)*2
// ---------------------------------------------------------------------------
__global__ void __launch_bounds__(256, 2)
ggcn_main(const float* __restrict__ eg,
          const float* __restrict__ bC,
          float* __restrict__ ws,
          float* __restrict__ out) {
    extern __shared__ char smem[];
    int tid = threadIdx.x;
    int lane = tid & 63, wid = tid >> 6;
    int bidx = blockIdx.x;
    int m = bidx >> 3;           // row 0..511
    int jt0 = (bidx & 7) * 32;   // j-tile start
    int bb = m >> 8;             // batch
    size_t ebase0 = (size_t)m * 65536 + (size_t)jt0 * 256;

    // ---- stage A (e tile, 32j x 256k) as bf16 hi/lo ----
#pragma unroll
    for (int r = 0; r < 8; ++r) {
        vfloat4 v = *(const vfloat4*)(eg + ebase0 + r * 1024 + tid * 4);
        int j = r * 4 + wid;          // (r*1024 + tid*4) >> 8
        int kg = lane >> 1;           // k0 = lane*4 -> kg = k0>>3
        int off = kg * 512 + (((j ^ kg) << 4) | ((lane & 1) * 8));
        vshort4 hi, lo;
#pragma unroll
        for (int t = 0; t < 4; ++t) {
            unsigned short h16 = bf16_rne(v[t]);
            float hf = __builtin_bit_cast(float, (unsigned)h16 << 16);
            hi[t] = (short)h16;
            lo[t] = (short)bf16_rne(v[t] - hf);
        }
        *(vshort4*)(smem + off) = hi;
        *(vshort4*)(smem + 16384 + off) = lo;
    }

    const char* wcb = (const char*)ws + WC_BYTE_OFF;
    auto loadB = [&](int s, int buf) {
        const char* src = wcb + s * 16384;
        char* dst = smem + 32768 + buf * 16384;
#pragma unroll
        for (int r = 0; r < 4; ++r) {
            int off = (wid * 4 + r) * 1024;
            gload_lds16(src + off + lane * 16, dst + off);
        }
    };
    loadB(0, 0);
    __syncthreads();

    int col = lane & 15, rgrp = lane >> 4;
    int wd0 = wid * 64;

    vfloat4 acc[2][4];
#pragma unroll
    for (int jf = 0; jf < 2; ++jf)
#pragma unroll
        for (int df = 0; df < 4; ++df) acc[jf][df] = (vfloat4){0.f, 0.f, 0.f, 0.f};

    for (int s = 0; s < 8; ++s) {
        int cur = s & 1;
        if (s < 7) loadB(s + 1, cur ^ 1);
        const char* bbuf = smem + 32768 + cur * 16384;
        int kgA = s * 4 + rgrp;
        vshort8 ah[2], al[2], bv[4];
#pragma unroll
        for (int jf = 0; jf < 2; ++jf) {
            int ab = kgA * 512 + (((jf * 16 + col) ^ kgA) << 4);
            ah[jf] = *(const vshort8*)(smem + ab);
            al[jf] = *(const vshort8*)(smem + 16384 + ab);
        }
#pragma unroll
        for (int df = 0; df < 4; ++df)
            bv[df] = *(const vshort8*)(bbuf + rgrp * 4096 + (wd0 + df * 16 + col) * 16);
#pragma unroll
        for (int jf = 0; jf < 2; ++jf)
#pragma unroll
            for (int df = 0; df < 4; ++df) {
                acc[jf][df] = mfma_16x16x32_bf16(ah[jf], bv[df], acc[jf][df]);
                acc[jf][df] = mfma_16x16x32_bf16(al[jf], bv[df], acc[jf][df]);
            }
        __syncthreads();
    }

    // ---- fused epilogue: bias + Ah/Bh broadcast + relu + residual + store
    //      + sigmoid gate * Vh partial reduction ----
    float bc[4], bh[4];
#pragma unroll
    for (int df = 0; df < 4; ++df) {
        int d = wd0 + df * 16 + col;
        bc[df] = bC[d];
        bh[df] = ws[BH_OFF + m * 256 + d];
    }
    float macc[4] = {0, 0, 0, 0};
    float* eo_out = out + 131072;
#pragma unroll
    for (int jf = 0; jf < 2; ++jf) {
#pragma unroll
        for (int r = 0; r < 4; ++r) {
            int jg = jt0 + jf * 16 + rgrp * 4 + r;
            size_t rowoff = (size_t)(bb * 256 + jg) * 256;
            size_t erow = (size_t)m * 65536 + (size_t)jg * 256;
#pragma unroll
            for (int df = 0; df < 4; ++df) {
                int d = wd0 + df * 16 + col;
                float ce = acc[jf][df][r] + bc[df];
                float en = ws[AH_OFF + rowoff + d] + bh[df] + ce;
                float eo = eg[erow + d] + fmaxf(en, 0.f);
                eo_out[erow + d] = eo;
                float g = __builtin_amdgcn_rcpf(1.f + __expf(-eo));
                macc[df] = fmaf(g, ws[VH_OFF + rowoff + d], macc[df]);
            }
        }
    }
#pragma unroll
    for (int df = 0; df < 4; ++df) {
        float v = macc[df];
        v += __shfl_xor(v, 16, 64);
        v += __shfl_xor(v, 32, 64);
        if (lane < 16)
            atomicAdd(&ws[MS_OFF + m * 256 + wd0 + df * 16 + col], v);
    }
}

// ---------------------------------------------------------------------------
// final: h_out = h + relu(Uh + msgs/deg)
// ---------------------------------------------------------------------------
__global__ void __launch_bounds__(256)
ggcn_final(const float* __restrict__ h, const int* __restrict__ adj,
           const float* __restrict__ ws, float* __restrict__ out) {
    __shared__ float parts[4];
    int m = blockIdx.x, tid = threadIdx.x;
    float v = (float)adj[m * 256 + tid];
#pragma unroll
    for (int o = 1; o < 64; o <<= 1) v += __shfl_xor(v, o, 64);
    if ((tid & 63) == 0) parts[tid >> 6] = v;
    __syncthreads();
    float deg = parts[0] + parts[1] + parts[2] + parts[3];
    int o = m * 256 + tid;
    out[o] = h[o] + fmaxf(0.f, ws[UH_OFF + o] + ws[MS_OFF + o] / deg);
}

extern "C" void kernel_launch(void* const* d_in, const int* in_sizes, int n_in,
                              void* d_out, int out_size, void* d_ws, size_t ws_size,
                              hipStream_t stream) {
    const float* h   = (const float*)d_in[0];
    const float* eg  = (const float*)d_in[1];
    const int*   adj = (const int*)d_in[2];
    const float* WA  = (const float*)d_in[3];
    const float* bA  = (const float*)d_in[4];
    const float* WB  = (const float*)d_in[5];
    const float* bB  = (const float*)d_in[6];
    const float* WC  = (const float*)d_in[7];
    const float* bC  = (const float*)d_in[8];
    const float* WU  = (const float*)d_in[9];
    const float* bU  = (const float*)d_in[10];
    const float* WV  = (const float*)d_in[11];
    const float* bV  = (const float*)d_in[12];
    float* out = (float*)d_out;
    float* ws  = (float*)d_ws;

    ggcn_prep<<<256, 256, 0, stream>>>(h, WA, bA, WB, bB, WC, WU, bU, WV, bV, ws);
    ggcn_main<<<4096, 256, 65536, stream>>>(eg, bC, ws, out);
    ggcn_final<<<512, 256, 0, stream>>>(h, adj, ws, out);
}

// Round 5
// 292.407 us; speedup vs baseline: 1.1419x; 1.1419x over previous
//
#include <hip/hip_runtime.h>
#include <cstdint>
#include <cstddef>

// GGCN layer fused kernels for MI355X (gfx950).  B=2, N=256, D=256 fixed.
//
// ws float layout:
//   Ah  [512*256] @ 0
//   Bh  [512*256] @ 131072
//   Uh  [512*256] @ 262144
//   Vh  [512*256] @ 393216
//   msgs[512*256] @ 524288
//   wc bf16 (pre-permuted, slab/kg-major) @ byte 2621440, 131072 bytes
// total ws need = 2752512 bytes.

#define AH_OFF 0
#define BH_OFF 131072
#define UH_OFF 262144
#define VH_OFF 393216
#define MS_OFF 524288
#define WC_BYTE_OFF 2621440

typedef __attribute__((ext_vector_type(4))) float vfloat4;
typedef __attribute__((ext_vector_type(4))) short vshort4;
typedef __attribute__((ext_vector_type(8))) short vshort8;

__device__ inline unsigned short bf16_rne(float x) {
    unsigned u = __builtin_bit_cast(unsigned, x);
    u += 0x7fffu + ((u >> 16) & 1u);
    return (unsigned short)(u >> 16);
}

__device__ inline float bf16_to_f(unsigned short h) {
    return __builtin_bit_cast(float, (unsigned)h << 16);
}

__device__ inline void gload_lds16(const void* g, void* l) {
    __builtin_amdgcn_global_load_lds(
        (const __attribute__((address_space(1))) void*)g,
        (__attribute__((address_space(3))) void*)l, 16, 0, 0);
}

__device__ inline vfloat4 mfma_16x16x32_bf16(vshort8 a, vshort8 b, vfloat4 c) {
    asm("v_mfma_f32_16x16x32_bf16 %0, %1, %2, %0" : "+v"(c) : "v"(a), "v"(b));
    return c;
}

// ---------------------------------------------------------------------------
// prep: blocks 0..255   -> [512x1024] = h @ [WA|WB|WU|WV] via MFMA 3-pass
//                          (h_hi*w_hi + h_lo*w_hi + h_hi*w_lo; ~fp32-exact)
//       blocks 256..319 -> WC -> bf16 permuted [slab8][kg4][d256][e8]
//       blocks 320..383 -> zero msgs
// GEMM block: 32 rows x 64 cols, 256 thr (4 waves, one 16-col strip each).
// LDS: A(h) hi [kg32][slot32][8e] @0 (16K), lo @16384 (16K);
//      B(W) dbuf 2x { hi [kg8][col64][8e] 8K, lo +8192 } @32768.
// ---------------------------------------------------------------------------
__global__ void __launch_bounds__(256)
ggcn_prep(const float* __restrict__ h,
          const float* __restrict__ WA, const float* __restrict__ bA,
          const float* __restrict__ WB, const float* __restrict__ bB,
          const float* __restrict__ WC,
          const float* __restrict__ WU, const float* __restrict__ bU,
          const float* __restrict__ WV, const float* __restrict__ bV,
          float* __restrict__ ws) {
    extern __shared__ char smem[];
    int bid = blockIdx.x, tid = threadIdx.x;

    if (bid < 256) {
        int rt = bid & 15;        // row-tile: rows rt*32..+31
        int ct = bid >> 4;        // col-tile: cols ct*64..+63 of [WA|WB|WU|WV]
        int mat = ct >> 2;        // matrix index, uniform per block
        const float* Wm = (mat == 0) ? WA : (mat == 1) ? WB : (mat == 2) ? WU : WV;
        int cm0 = (ct & 3) * 64;  // col base within matrix

        // ---- stage A = h[rt*32..+31][0..255] as hi/lo bf16 ----
#pragma unroll
        for (int r = 0; r < 8; ++r) {
            int flat = r * 1024 + tid * 4;
            int row_l = flat >> 8, k = flat & 255;
            vfloat4 v = *(const vfloat4*)(h + (rt * 32 + row_l) * 256 + k);
            int kg = k >> 3;
            int off = kg * 512 + (((row_l ^ kg) << 4) | ((k & 7) * 2));
            vshort4 hi, lo;
#pragma unroll
            for (int t = 0; t < 4; ++t) {
                unsigned short h16 = bf16_rne(v[t]);
                hi[t] = (short)h16;
                lo[t] = (short)bf16_rne(v[t] - bf16_to_f(h16));
            }
            *(vshort4*)(smem + off) = hi;
            *(vshort4*)(smem + 16384 + off) = lo;
        }

        // ---- W slab stager: slab s = k rows s*64..+63, cols cm0..+63 ----
        auto stageW = [&](int s, int buf) {
            char* base = smem + 32768 + buf * 16384;
#pragma unroll
            for (int rr = 0; rr < 4; ++rr) {
                int k_l = rr * 16 + (tid >> 4);
                int c_l = (tid & 15) * 4;
                vfloat4 v = *(const vfloat4*)(Wm + (s * 64 + k_l) * 256 + cm0 + c_l);
                int boff = (k_l >> 3) * 1024 + (k_l & 7) * 2;
#pragma unroll
                for (int t = 0; t < 4; ++t) {
                    unsigned short h16 = bf16_rne(v[t]);
                    unsigned short l16 = bf16_rne(v[t] - bf16_to_f(h16));
                    *(unsigned short*)(base + boff + (c_l + t) * 16) = h16;
                    *(unsigned short*)(base + 8192 + boff + (c_l + t) * 16) = l16;
                }
            }
        };
        stageW(0, 0);
        __syncthreads();

        int lane = tid & 63, w = tid >> 6;
        int col = lane & 15, rgrp = lane >> 4;
        int c_lane = w * 16 + col;

        vfloat4 acc[2];
        acc[0] = (vfloat4){0.f, 0.f, 0.f, 0.f};
        acc[1] = (vfloat4){0.f, 0.f, 0.f, 0.f};

        for (int s = 0; s < 4; ++s) {
            if (s < 3) stageW(s + 1, (s + 1) & 1);
            const char* bbuf = smem + 32768 + (s & 1) * 16384;
#pragma unroll
            for (int step = 0; step < 2; ++step) {
                int kgB = step * 4 + rgrp;
                vshort8 bhi = *(const vshort8*)(bbuf + kgB * 1024 + c_lane * 16);
                vshort8 blo = *(const vshort8*)(bbuf + 8192 + kgB * 1024 + c_lane * 16);
                int kgA = s * 8 + kgB;
#pragma unroll
                for (int mf = 0; mf < 2; ++mf) {
                    int ab = kgA * 512 + (((mf * 16 + col) ^ kgA) << 4);
                    vshort8 ahi = *(const vshort8*)(smem + ab);
                    vshort8 alo = *(const vshort8*)(smem + 16384 + ab);
                    acc[mf] = mfma_16x16x32_bf16(ahi, bhi, acc[mf]);
                    acc[mf] = mfma_16x16x32_bf16(alo, bhi, acc[mf]);
                    acc[mf] = mfma_16x16x32_bf16(ahi, blo, acc[mf]);
                }
            }
            __syncthreads();
        }

        // ---- epilogue: add bias, write to the right ws plane ----
        const float* bp = (mat == 0) ? bA : (mat == 1) ? bB : (mat == 2) ? bU : bV;
        int cm = cm0 + c_lane;
        float bias = bp[cm];
        float* ob = ws + (mat == 0 ? AH_OFF : mat == 1 ? BH_OFF : mat == 2 ? UH_OFF : VH_OFF);
#pragma unroll
        for (int mf = 0; mf < 2; ++mf)
#pragma unroll
            for (int rr = 0; rr < 4; ++rr) {
                int row = rt * 32 + mf * 16 + rgrp * 4 + rr;
                ob[row * 256 + cm] = acc[mf][rr] + bias;
            }
    } else if (bid < 320) {
        // WC -> bf16 permute: wc[idx], idx = slab*8192+kg*2048+d*8+e,
        // k = slab*32+kg*8+e
        unsigned short* wc = (unsigned short*)((char*)ws + WC_BYTE_OFF);
        int local = bid - 256;
#pragma unroll
        for (int r = 0; r < 4; ++r) {
            int idx = local * 1024 + r * 256 + tid;
            int slab = idx >> 13;
            int kg = (idx >> 11) & 3;
            int d = (idx >> 3) & 255;
            int e = idx & 7;
            int k = slab * 32 + kg * 8 + e;
            wc[idx] = bf16_rne(WC[k * 256 + d]);
        }
    } else {
        int local = bid - 320;
#pragma unroll
        for (int r = 0; r < 8; ++r)
            ws[MS_OFF + local * 2048 + r * 256 + tid] = 0.f;
    }
}

// ---------------------------------------------------------------------------
// main: grid 4096 = 512 rows x 8 j-tiles of 32. block 512 thr (8 waves:
// wave = (jh = wid>>2) x (dq = wid&3); each wave 16 j-rows x 64 d-cols).
// LDS 64KB -> 2 blocks/CU (16 waves):
//   A_hi [kg32][slot32][8e] @0 (16K), A_lo @16384 (16K)
//   B dbuf 2x [kg4][d256][8e] @32768 (2x16K)
// ---------------------------------------------------------------------------
__global__ void __launch_bounds__(512, 4)
ggcn_main(const float* __restrict__ eg,
          const float* __restrict__ bC,
          float* __restrict__ ws,
          float* __restrict__ out) {
    extern __shared__ char smem[];
    int tid = threadIdx.x;
    int lane = tid & 63, wid = tid >> 6;
    int bidx = blockIdx.x;
    int m = bidx >> 3;           // row 0..511
    int jt0 = (bidx & 7) * 32;   // j-tile start
    int bb = m >> 8;             // batch
    size_t ebase0 = (size_t)m * 65536 + (size_t)jt0 * 256;

    // ---- stage A (e tile, 32j x 256k) as bf16 hi/lo ----
#pragma unroll
    for (int r = 0; r < 4; ++r) {
        int flat = r * 2048 + tid * 4;
        vfloat4 v = *(const vfloat4*)(eg + ebase0 + flat);
        int j = flat >> 8;            // r*8 + wid
        int k = flat & 255;           // (lane)*4
        int kg = k >> 3;
        int off = kg * 512 + (((j ^ kg) << 4) | ((k & 7) * 2));
        vshort4 hi, lo;
#pragma unroll
        for (int t = 0; t < 4; ++t) {
            unsigned short h16 = bf16_rne(v[t]);
            hi[t] = (short)h16;
            lo[t] = (short)bf16_rne(v[t] - bf16_to_f(h16));
        }
        *(vshort4*)(smem + off) = hi;
        *(vshort4*)(smem + 16384 + off) = lo;
    }

    // ---- B slab stager: canonical global_load_lds form ----
    // dst is WAVE-UNIFORM; HW scatters lane*16. src carries the lane offset.
    const char* wcb = (const char*)ws + WC_BYTE_OFF;
    auto loadB = [&](int s, int buf) {
        const char* src = wcb + s * 16384;
        char* dst = smem + 32768 + buf * 16384;
#pragma unroll
        for (int rr = 0; rr < 2; ++rr) {
            int off_u = (rr * 8 + wid) * 1024;   // wave-uniform
            gload_lds16(src + off_u + lane * 16, dst + off_u);
        }
    };
    loadB(0, 0);
    __syncthreads();

    int col = lane & 15, rgrp = lane >> 4;
    int jh = wid >> 2, dq = wid & 3;
    int d0 = dq * 64;

    vfloat4 acc[4];
#pragma unroll
    for (int df = 0; df < 4; ++df) acc[df] = (vfloat4){0.f, 0.f, 0.f, 0.f};

    for (int s = 0; s < 8; ++s) {
        int cur = s & 1;
        if (s < 7) loadB(s + 1, cur ^ 1);
        const char* bbuf = smem + 32768 + cur * 16384;
        int kgA = s * 4 + rgrp;
        int ab = kgA * 512 + (((jh * 16 + col) ^ kgA) << 4);
        vshort8 ah = *(const vshort8*)(smem + ab);
        vshort8 al = *(const vshort8*)(smem + 16384 + ab);
        vshort8 bv[4];
#pragma unroll
        for (int df = 0; df < 4; ++df)
            bv[df] = *(const vshort8*)(bbuf + rgrp * 4096 + (d0 + df * 16 + col) * 16);
#pragma unroll
        for (int df = 0; df < 4; ++df) {
            acc[df] = mfma_16x16x32_bf16(ah, bv[df], acc[df]);
            acc[df] = mfma_16x16x32_bf16(al, bv[df], acc[df]);
        }
        __syncthreads();
    }

    // ---- fused epilogue: bias + Ah/Bh broadcast + relu + residual + store
    //      + sigmoid gate * Vh partial reduction. e reconstructed from LDS.
    float bc[4], bh[4];
#pragma unroll
    for (int df = 0; df < 4; ++df) {
        int d = d0 + df * 16 + col;
        bc[df] = bC[d];
        bh[df] = ws[BH_OFF + m * 256 + d];
    }
    float macc[4] = {0, 0, 0, 0};
    float* eo_out = out + 131072;
#pragma unroll
    for (int r = 0; r < 4; ++r) {
        int jl = jh * 16 + rgrp * 4 + r;
        int jg = jt0 + jl;
        size_t rowoff = (size_t)(bb * 256 + jg) * 256;
        size_t erow = (size_t)m * 65536 + (size_t)jg * 256;
#pragma unroll
        for (int df = 0; df < 4; ++df) {
            int d = d0 + df * 16 + col;
            int kg = d >> 3;
            int aoff = kg * 512 + (((jl ^ kg) << 4) | ((d & 7) * 2));
            float ev = bf16_to_f(*(const unsigned short*)(smem + aoff)) +
                       bf16_to_f(*(const unsigned short*)(smem + 16384 + aoff));
            float ce = acc[df][r] + bc[df];
            float en = ws[AH_OFF + rowoff + d] + bh[df] + ce;
            float eo = ev + fmaxf(en, 0.f);
            eo_out[erow + d] = eo;
            float g = __builtin_amdgcn_rcpf(1.f + __expf(-eo));
            macc[df] = fmaf(g, ws[VH_OFF + rowoff + d], macc[df]);
        }
    }
#pragma unroll
    for (int df = 0; df < 4; ++df) {
        float v = macc[df];
        v += __shfl_xor(v, 16, 64);
        v += __shfl_xor(v, 32, 64);
        if (lane < 16)
            atomicAdd(&ws[MS_OFF + m * 256 + d0 + df * 16 + col], v);
    }
}

// ---------------------------------------------------------------------------
// final: h_out = h + relu(Uh + msgs/deg)
// ---------------------------------------------------------------------------
__global__ void __launch_bounds__(256)
ggcn_final(const float* __restrict__ h, const int* __restrict__ adj,
           const float* __restrict__ ws, float* __restrict__ out) {
    __shared__ float parts[4];
    int m = blockIdx.x, tid = threadIdx.x;
    float v = (float)adj[m * 256 + tid];
#pragma unroll
    for (int o = 1; o < 64; o <<= 1) v += __shfl_xor(v, o, 64);
    if ((tid & 63) == 0) parts[tid >> 6] = v;
    __syncthreads();
    float deg = parts[0] + parts[1] + parts[2] + parts[3];
    int o = m * 256 + tid;
    out[o] = h[o] + fmaxf(0.f, ws[UH_OFF + o] + ws[MS_OFF + o] / deg);
}

extern "C" void kernel_launch(void* const* d_in, const int* in_sizes, int n_in,
                              void* d_out, int out_size, void* d_ws, size_t ws_size,
                              hipStream_t stream) {
    const float* h   = (const float*)d_in[0];
    const float* eg  = (const float*)d_in[1];
    const int*   adj = (const int*)d_in[2];
    const float* WA  = (const float*)d_in[3];
    const float* bA  = (const float*)d_in[4];
    const float* WB  = (const float*)d_in[5];
    const float* bB  = (const float*)d_in[6];
    const float* WC  = (const float*)d_in[7];
    const float* bC  = (const float*)d_in[8];
    const float* WU  = (const float*)d_in[9];
    const float* bU  = (const float*)d_in[10];
    const float* WV  = (const float*)d_in[11];
    const float* bV  = (const float*)d_in[12];
    float* out = (float*)d_out;
    float* ws  = (float*)d_ws;

    ggcn_prep<<<384, 256, 65536, stream>>>(h, WA, bA, WB, bB, WC, WU, bU, WV, bV, ws);
    ggcn_main<<<4096, 512, 65536, stream>>>(eg, bC, ws, out);
    ggcn_final<<<512, 256, 0, stream>>>(h, adj, ws, out);
}